// Round 8
// baseline (91.704 us; speedup 1.0000x reference)
//
#include <hip/hip_runtime.h>

#define NB 32
#define NS 2048
// (1/sqrt(d_k)) * log2(e) folded into q so scores feed v_exp_f32 (2^x) directly
#define QS 0.72134752044448170367f

typedef _Float16 f16;
typedef _Float16 h2 __attribute__((ext_vector_type(2)));
typedef _Float16 h4 __attribute__((ext_vector_type(4)));
typedef _Float16 h8 __attribute__((ext_vector_type(8)));
typedef float f32x4 __attribute__((ext_vector_type(4)));

__device__ __forceinline__ h2 cvt_pk_f16(float a, float b) {
  return __builtin_bit_cast(h2, __builtin_amdgcn_cvt_pkrtz(a, b));
}
__device__ __forceinline__ f32x4 mfma16(h4 a, h4 b, f32x4 c) {
  return __builtin_amdgcn_mfma_f32_16x16x16f16(a, b, c, 0, 0, 0);
}

// LDS geometry (units: halves/f16):
//   main      : [1024][8]  f16 k-rows (16 B/row)            -> 8192 halves
//   transposed: [10][1032] f16, row d = dim (0-7), 8 = ones, 9 = zeros
//               stride 1032 halves (2064 B) to spread banks  -> 10320 halves
#define TR_STRIDE 1032
#define TR_BASE 8192
#define LDS_HALVES (8192 + 10 * 1032)
#define ZIDX (TR_BASE + 9 * TR_STRIDE)  // zeros row (zero-fragment source)

// ---------------------------------------------------------------------------
// All-MFMA K=16 fused attention + 2-way split-K at 8 waves/SIMD (R8).
//   R6 retry: split-K failed ONLY via spills (h8-packing kernel > 64-reg cap
//   under launch_bounds(512,8); WRITE_SIZE 2->36 MB). R7's K=16 loop removed
//   the packing temps; additionally the chunk-1 register prefetch (16 VGPRs)
//   is dropped -- x is 2 MB total, fully L2-resident, and at 8 waves/SIMD
//   the mid-kernel restage's global loads are hidden by 31 other waves/CU.
//   - block = 512 thr = 8 waves, owns 64 q. wave w: q-tile qt=w&3 (16 q),
//     k-half h=w>>2 (rows [h*512, h*512+512) of each 1024-row chunk).
//   - grid = 32 x 32 = 1024 blocks -> 4 blocks/CU (LDS 149.5/160 KB),
//     32 waves/CU = 8 waves/SIMD. Same total work, 2x wave pool to fill
//     the ds_read -> scoreMFMA -> exp -> PV-MFMA dependency bubbles
//     (R5 measured ~39% issue-idle at 4 waves/SIMD).
//   - SCORES via mfma_f32_16x16x16_f16: A = K-rows (g=0 lanes read main
//     [(r0+n)*8], one b128 covers both heads; g>0 lanes read zeros row),
//     B = Q[n][d]*QS (loop-invariant regs, g>0 zero). kappa_A == kappa_B
//     -> exact for any HW slot map (R4/R5/R7-proven cancellation).
//   - D layout: col = lane&15 = q, row = 4g+reg -> exp+cvt_pk gives the h4
//     that IS the PV B-fragment (slot j of group g = k-slot 4g+j).
//   - PV: A = h^T rows (m<4 -> dim head*4+m; m==4 -> ones = denominator;
//     else zeros), one ds_read_b64 per head from the transposed copy.
//   - epilogue: wave pairs (w, w+4) merge C via LDS (stride 9 floats ->
//     2-way bank aliasing = free), then h==0 waves normalize/project/store.
// ---------------------------------------------------------------------------
__global__ __launch_bounds__(512, 8) void attn_fused_kernel(
    const float* __restrict__ x, const float* __restrict__ theta,
    const float* __restrict__ Wout, float* __restrict__ outp) {
  __shared__ __align__(16) f16 lds[LDS_HALVES];

  const int b = blockIdx.y;
  const int t = threadIdx.x;
  const int w = t >> 6;
  const int lane = t & 63;
  const int g = lane >> 4;  // 16-lane group
  const int n = lane & 15;  // q-col (B role) AND k/dim-row m (A role)
  const int qt = w & 3;     // q-tile within block
  const int h = w >> 2;     // k-half of each chunk

  float th[8];
#pragma unroll
  for (int e = 0; e < 8; ++e) th[e] = theta[e];

  // ---- stage chunk 0 (k rows 0..1023): main f16 rows + transposed copy ----
#pragma unroll
  for (int i = 0; i < 2; ++i) {
    const int l = t + 512 * i;
    const float4* xr = (const float4*)(x + ((size_t)b * NS + l) * 8);
    float4 lo = xr[0], hi = xr[1];
    h8 hv;
    hv[0] = (f16)__cosf(lo.x + th[0]);
    hv[1] = (f16)__cosf(lo.y + th[1]);
    hv[2] = (f16)__cosf(lo.z + th[2]);
    hv[3] = (f16)__cosf(lo.w + th[3]);
    hv[4] = (f16)__cosf(hi.x + th[4]);
    hv[5] = (f16)__cosf(hi.y + th[5]);
    hv[6] = (f16)__cosf(hi.z + th[6]);
    hv[7] = (f16)__cosf(hi.w + th[7]);
    ((h8*)lds)[l] = hv;
#pragma unroll
    for (int e = 0; e < 8; ++e) lds[TR_BASE + e * TR_STRIDE + l] = hv[e];
    lds[TR_BASE + 8 * TR_STRIDE + l] = (f16)1.0f;  // ones row (denominator)
    lds[ZIDX + l] = (f16)0.0f;                     // zeros row
  }

  // ---- loop-invariant score B-fragments: Q[n][d]*QS (g==0 lanes only) ----
  h4 Bq0 = {(f16)0.f, (f16)0.f, (f16)0.f, (f16)0.f};
  h4 Bq1 = Bq0;
  if (g == 0) {
    const float4* xq = (const float4*)(
        x + ((size_t)b * NS + blockIdx.x * 64 + qt * 16 + n) * 8);
    float4 lo = xq[0], hi = xq[1];
    Bq0[0] = (f16)(__cosf(lo.x + th[0]) * QS);
    Bq0[1] = (f16)(__cosf(lo.y + th[1]) * QS);
    Bq0[2] = (f16)(__cosf(lo.z + th[2]) * QS);
    Bq0[3] = (f16)(__cosf(lo.w + th[3]) * QS);
    Bq1[0] = (f16)(__cosf(hi.x + th[4]) * QS);
    Bq1[1] = (f16)(__cosf(hi.y + th[5]) * QS);
    Bq1[2] = (f16)(__cosf(hi.z + th[6]) * QS);
    Bq1[3] = (f16)(__cosf(hi.w + th[7]) * QS);
  }

  // score A-frag source: g==0 lanes read k-row (r0+n) of this wave's half
  // (both heads in one b128), advancing 16 rows/kk; g>0 read the zeros row.
  const int sini = (g == 0) ? (h * 512 + n) * 8 : ZIDX;
  const int sadv = (g == 0) ? 128 : 0;

  // PV A-frag source rows in the transposed copy, per head:
  //   m<4 -> dim (head*4+m); m==4 -> ones; m>4 -> zeros
  const int d0 = (n < 4) ? n : ((n == 4) ? 8 : 9);
  const int d1 = (n < 4) ? (n + 4) : d0;
  const int t0ini = TR_BASE + d0 * TR_STRIDE + h * 512 + 4 * g;
  const int t1ini = TR_BASE + d1 * TR_STRIDE + h * 512 + 4 * g;

  const f32x4 Z = {0.f, 0.f, 0.f, 0.f};
  f32x4 C0 = Z;  // head0: rows 0-3 = dims, row 4 = den (col = q)
  f32x4 C1 = Z;  // head1

  __syncthreads();  // (1) chunk 0 staged

  for (int chunk = 0; chunk < 2; ++chunk) {
    if (chunk == 1) {
      __syncthreads();  // (2) chunk 0 fully consumed
      // restage chunk 1 straight from global (L2-resident; latency hidden
      // by 8 waves/SIMD -- no register prefetch, keeps VGPR under the
      // 64-reg cap that sank R6)
#pragma unroll
      for (int i = 0; i < 2; ++i) {
        const int l = t + 512 * i;
        const float4* xr = (const float4*)(x + ((size_t)b * NS + 1024 + l) * 8);
        float4 lo = xr[0], hi = xr[1];
        h8 hv;
        hv[0] = (f16)__cosf(lo.x + th[0]);
        hv[1] = (f16)__cosf(lo.y + th[1]);
        hv[2] = (f16)__cosf(lo.z + th[2]);
        hv[3] = (f16)__cosf(lo.w + th[3]);
        hv[4] = (f16)__cosf(hi.x + th[4]);
        hv[5] = (f16)__cosf(hi.y + th[5]);
        hv[6] = (f16)__cosf(hi.z + th[6]);
        hv[7] = (f16)__cosf(hi.w + th[7]);
        ((h8*)lds)[l] = hv;
#pragma unroll
        for (int e = 0; e < 8; ++e) lds[TR_BASE + e * TR_STRIDE + l] = hv[e];
      }
      __syncthreads();  // (3) chunk 1 staged
    }

    int sa = sini;
    int ta0 = t0ini;
    int ta1 = t1ini;
#pragma unroll 4
    for (int kk = 0; kk < 32; ++kk) {
      // one b128: head0 dims in halves 0-3, head1 in 4-7 (zeros for g>0)
      h8 kr = *(const h8*)(lds + sa);
      h4 a0 = __builtin_shufflevector(kr, kr, 0, 1, 2, 3);
      h4 a1 = __builtin_shufflevector(kr, kr, 4, 5, 6, 7);
      // PV A-frags: h^T (+ones/zeros) at cols r0+4g..+3, one b64 per head
      h4 v0 = *(const h4*)(lds + ta0);
      h4 v1 = *(const h4*)(lds + ta1);

      // scores: D row = k-offset 4g+reg, col = q
      f32x4 S0 = mfma16(a0, Bq0, Z);
      f32x4 S1 = mfma16(a1, Bq1, Z);

      // exp (trans pipe) + pack: h4 IS the PV B-fragment
      h4 p0, p1;
      h2 u;
      u = cvt_pk_f16(__builtin_amdgcn_exp2f(S0[0]),
                     __builtin_amdgcn_exp2f(S0[1]));
      p0[0] = u[0];
      p0[1] = u[1];
      u = cvt_pk_f16(__builtin_amdgcn_exp2f(S0[2]),
                     __builtin_amdgcn_exp2f(S0[3]));
      p0[2] = u[0];
      p0[3] = u[1];
      u = cvt_pk_f16(__builtin_amdgcn_exp2f(S1[0]),
                     __builtin_amdgcn_exp2f(S1[1]));
      p1[0] = u[0];
      p1[1] = u[1];
      u = cvt_pk_f16(__builtin_amdgcn_exp2f(S1[2]),
                     __builtin_amdgcn_exp2f(S1[3]));
      p1[2] = u[0];
      p1[3] = u[1];

      // PV (+denominator via ones-row) on the MFMA pipe
      C0 = mfma16(v0, p0, C0);
      C1 = mfma16(v1, p1, C1);

      sa += sadv;
      ta0 += 16;
      ta1 += 16;
    }
  }

  // ---- split-K pair merge (w <-> w+4) through LDS ----
  __syncthreads();  // (4) all waves done reading lds as k-tiles
  float* kvf = (float*)lds;
  if (h == 1) {
    // stride 9 floats: lanes i and i+32 alias (2-way = free), else distinct
    float* mb = kvf + ((size_t)(qt * 64 + lane)) * 9;
    mb[0] = C0[0];
    mb[1] = C0[1];
    mb[2] = C0[2];
    mb[3] = C0[3];
    mb[4] = C1[0];
    mb[5] = C1[1];
    mb[6] = C1[2];
    mb[7] = C1[3];
  }
  __syncthreads();  // (5)
  if (h == 0) {
    const float* mb = kvf + ((size_t)(qt * 64 + lane)) * 9;
    C0[0] += mb[0];
    C0[1] += mb[1];
    C0[2] += mb[2];
    C0[3] += mb[3];
    C1[0] += mb[4];
    C1[1] += mb[5];
    C1[2] += mb[6];
    C1[3] += mb[7];

    // ---- epilogue: C cols = q (lane&15), rows = 4*(lane>>4)+reg ----
    const float den0 = __shfl(C0[0], 16 + n, 64);  // row 4 = ones-row sum
    const float den1 = __shfl(C1[0], 16 + n, 64);
    if (lane < 16) {  // group 0 holds rows 0-3 = numerator dims
      const float i0 = 1.0f / den0, i1 = 1.0f / den1;
      float m8[8] = {C0[0] * i0, C0[1] * i0, C0[2] * i0, C0[3] * i0,
                     C1[0] * i1, C1[1] * i1, C1[2] * i1, C1[3] * i1};
      float o[8];
#pragma unroll
      for (int e = 0; e < 8; ++e) {
        float s = 0.f;
#pragma unroll
        for (int f = 0; f < 8; ++f) s += m8[f] * Wout[e * 8 + f];
        o[e] = s;
      }
      const int q = blockIdx.x * 64 + qt * 16 + n;
      float4* op = (float4*)(outp + ((size_t)b * NS + q) * 8);
      op[0] = make_float4(o[0], o[1], o[2], o[3]);
      op[1] = make_float4(o[4], o[5], o[6], o[7]);
    }
  }
}

extern "C" void kernel_launch(void* const* d_in, const int* in_sizes, int n_in,
                              void* d_out, int out_size, void* d_ws,
                              size_t ws_size, hipStream_t stream) {
  const float* x = (const float*)d_in[0];      // [32, 2048, 8]
  const float* theta = (const float*)d_in[1];  // [8]
  const float* W = (const float*)d_in[2];      // [8, 8]
  float* out = (float*)d_out;                  // [32, 2048, 8]
  (void)d_ws;
  (void)ws_size;

  // 1024 blocks (32 q-supertiles x 32 batches) of 8 waves; 37.4 KB LDS each
  // -> 4 blocks/CU (149.5/160 KB), 32 waves/CU = 8 waves/SIMD.
  attn_fused_kernel<<<dim3(NS / 64, NB), 512, 0, stream>>>(x, theta, W, out);
}

// Round 10
// 87.774 us; speedup vs baseline: 1.0448x; 1.0448x over previous
//
#include <hip/hip_runtime.h>

#define NB 32
#define NS 2048
// (1/sqrt(d_k)) * log2(e) folded into q so scores feed v_exp_f32 (2^x) directly
#define QS 0.72134752044448170367f

typedef _Float16 f16;
typedef _Float16 h2 __attribute__((ext_vector_type(2)));
typedef _Float16 h4 __attribute__((ext_vector_type(4)));
typedef _Float16 h8 __attribute__((ext_vector_type(8)));
typedef float f32x4 __attribute__((ext_vector_type(4)));

__device__ __forceinline__ h2 cvt_pk_f16(float a, float b) {
  return __builtin_bit_cast(h2, __builtin_amdgcn_cvt_pkrtz(a, b));
}
__device__ __forceinline__ f32x4 mfma16(h4 a, h4 b, f32x4 c) {
  return __builtin_amdgcn_mfma_f32_16x16x16f16(a, b, c, 0, 0, 0);
}

// LDS geometry (units: halves/f16):
//   main      : [1024][8]  f16 k-rows (16 B/row)            -> 8192 halves
//   transposed: [10][1032] f16, row d = dim (0-7), 8 = ones, 9 = zeros
//               stride 1032 halves (2064 B) to spread banks  -> 10320 halves
#define TR_STRIDE 1032
#define TR_BASE 8192
#define LDS_HALVES (8192 + 10 * 1032)
#define ZIDX (TR_BASE + 9 * TR_STRIDE)  // zeros row (zero-fragment source)

// ---------------------------------------------------------------------------
// All-MFMA K=16 fused attention, DUAL-STREAM ILP (R9, resubmitted after
// container-infra failure).
//   R8 post-mortem: 8 waves/SIMD is unreachable -- the 64-reg cap spills the
//   accumulators (WRITE_SIZE 16 MB = exactly C0+C1 per thread); occupancy is
//   a closed lever at 4 waves/SIMD. R8 counters show ~40% issue-idle with
//   per-pipe floors well below wall => DEPENDENCY-LATENCY bound: one serial
//   ds_read -> S-MFMA -> exp x8 -> cvt -> PV-MFMA chain per wave.
//   Fix: TWO independent k-streams per wave (rows [0,512) and [512,1024) of
//   each chunk), separate accumulators C*a/C*b -> 2x dependency distance at
//   constant instruction count. Merge = 8 register adds at the end (free).
//   - block = 512 thr = 8 waves; block owns 128 q (wave w owns 16 q).
//   - grid 512 blocks -> 2 blocks/CU, 4 waves/SIMD, launch_bounds(512,4)
//     (128-reg cap: dual-stream needs ~70 VGPR, no spills).
//   - SCORES via mfma_f32_16x16x16_f16: A = K-rows (g=0 lanes read main
//     [(r0+n)*8], one b128 covers both heads; g>0 lanes read zeros row),
//     B = Q[n][d]*QS (loop-invariant regs, g>0 zero). kappa_A == kappa_B
//     -> exact for any HW slot map (R4/R5/R7-proven cancellation).
//   - D layout: col = lane&15 = q, row = 4g+reg -> exp+cvt_pk gives the h4
//     that IS the PV B-fragment (slot j of group g = k-slot 4g+j).
//   - PV: A = h^T rows (m<4 -> dim head*4+m; m==4 -> ones = denominator;
//     else zeros), one ds_read_b64 per head per stream.
//   - epilogue per-wave: group 0 lanes hold dims (rows 0-3), row 4 = den.
// ---------------------------------------------------------------------------
__global__ __launch_bounds__(512, 4) void attn_fused_kernel(
    const float* __restrict__ x, const float* __restrict__ theta,
    const float* __restrict__ Wout, float* __restrict__ outp) {
  __shared__ __align__(16) f16 lds[LDS_HALVES];

  const int b = blockIdx.y;
  const int t = threadIdx.x;
  const int w = t >> 6;
  const int lane = t & 63;
  const int g = lane >> 4;  // 16-lane group
  const int n = lane & 15;  // q-col (B role) AND k/dim-row m (A role)

  float th[8];
#pragma unroll
  for (int e = 0; e < 8; ++e) th[e] = theta[e];

  // ---- stage chunk 0 (k rows 0..1023): main f16 rows + transposed copy ----
#pragma unroll
  for (int i = 0; i < 2; ++i) {
    const int l = t + 512 * i;
    const float4* xr = (const float4*)(x + ((size_t)b * NS + l) * 8);
    float4 lo = xr[0], hi = xr[1];
    h8 hv;
    hv[0] = (f16)__cosf(lo.x + th[0]);
    hv[1] = (f16)__cosf(lo.y + th[1]);
    hv[2] = (f16)__cosf(lo.z + th[2]);
    hv[3] = (f16)__cosf(lo.w + th[3]);
    hv[4] = (f16)__cosf(hi.x + th[4]);
    hv[5] = (f16)__cosf(hi.y + th[5]);
    hv[6] = (f16)__cosf(hi.z + th[6]);
    hv[7] = (f16)__cosf(hi.w + th[7]);
    ((h8*)lds)[l] = hv;
#pragma unroll
    for (int e = 0; e < 8; ++e) lds[TR_BASE + e * TR_STRIDE + l] = hv[e];
    lds[TR_BASE + 8 * TR_STRIDE + l] = (f16)1.0f;  // ones row (denominator)
    lds[ZIDX + l] = (f16)0.0f;                     // zeros row
  }

  // ---- prefetch chunk 1 raw x into registers ----
  float4 pf[2][2];
#pragma unroll
  for (int i = 0; i < 2; ++i) {
    const int l = t + 512 * i;
    const float4* xr = (const float4*)(x + ((size_t)b * NS + 1024 + l) * 8);
    pf[i][0] = xr[0];
    pf[i][1] = xr[1];
  }

  // ---- loop-invariant score B-fragments: Q[n][d]*QS (g==0 lanes only) ----
  h4 Bq0 = {(f16)0.f, (f16)0.f, (f16)0.f, (f16)0.f};
  h4 Bq1 = Bq0;
  if (g == 0) {
    const float4* xq = (const float4*)(
        x + ((size_t)b * NS + blockIdx.x * 128 + w * 16 + n) * 8);
    float4 lo = xq[0], hi = xq[1];
    Bq0[0] = (f16)(__cosf(lo.x + th[0]) * QS);
    Bq0[1] = (f16)(__cosf(lo.y + th[1]) * QS);
    Bq0[2] = (f16)(__cosf(lo.z + th[2]) * QS);
    Bq0[3] = (f16)(__cosf(lo.w + th[3]) * QS);
    Bq1[0] = (f16)(__cosf(hi.x + th[4]) * QS);
    Bq1[1] = (f16)(__cosf(hi.y + th[5]) * QS);
    Bq1[2] = (f16)(__cosf(hi.z + th[6]) * QS);
    Bq1[3] = (f16)(__cosf(hi.w + th[7]) * QS);
  }

  // stream A: k-rows [r0, r0+16) walking [0,512); stream B: +512 rows.
  // g==0 lanes read k-row (r0+n), both heads in one b128; g>0 zeros row.
  const int sinA = (g == 0) ? n * 8 : ZIDX;
  const int sinB = (g == 0) ? (512 + n) * 8 : ZIDX;
  const int sadv = (g == 0) ? 128 : 0;

  // PV A-frag source rows in the transposed copy, per head:
  //   m<4 -> dim (head*4+m); m==4 -> ones; m>4 -> zeros
  const int d0 = (n < 4) ? n : ((n == 4) ? 8 : 9);
  const int d1 = (n < 4) ? (n + 4) : d0;
  const int tA0i = TR_BASE + d0 * TR_STRIDE + 4 * g;
  const int tA1i = TR_BASE + d1 * TR_STRIDE + 4 * g;

  const f32x4 Z = {0.f, 0.f, 0.f, 0.f};
  f32x4 C0a = Z, C1a = Z;  // stream A accumulators (head0, head1)
  f32x4 C0b = Z, C1b = Z;  // stream B accumulators

  __syncthreads();  // (1) chunk 0 staged

  for (int chunk = 0; chunk < 2; ++chunk) {
    if (chunk == 1) {
      __syncthreads();  // (2) chunk 0 fully consumed
      // restage chunk 1 from prefetched registers (no memory latency)
#pragma unroll
      for (int i = 0; i < 2; ++i) {
        const int l = t + 512 * i;
        float4 lo = pf[i][0], hi = pf[i][1];
        h8 hv;
        hv[0] = (f16)__cosf(lo.x + th[0]);
        hv[1] = (f16)__cosf(lo.y + th[1]);
        hv[2] = (f16)__cosf(lo.z + th[2]);
        hv[3] = (f16)__cosf(lo.w + th[3]);
        hv[4] = (f16)__cosf(hi.x + th[4]);
        hv[5] = (f16)__cosf(hi.y + th[5]);
        hv[6] = (f16)__cosf(hi.z + th[6]);
        hv[7] = (f16)__cosf(hi.w + th[7]);
        ((h8*)lds)[l] = hv;
#pragma unroll
        for (int e = 0; e < 8; ++e) lds[TR_BASE + e * TR_STRIDE + l] = hv[e];
      }
      __syncthreads();  // (3) chunk 1 staged
    }

    int sa = sinA, sb = sinB;
    int ta0 = tA0i, ta1 = tA1i;
    int tb0 = tA0i + 512, tb1 = tA1i + 512;
#pragma unroll 2
    for (int kk = 0; kk < 32; ++kk) {
      // ---- both streams' fragment loads (independent, issue together) ----
      h8 krA = *(const h8*)(lds + sa);
      h8 krB = *(const h8*)(lds + sb);
      h4 vA0 = *(const h4*)(lds + ta0);
      h4 vA1 = *(const h4*)(lds + ta1);
      h4 vB0 = *(const h4*)(lds + tb0);
      h4 vB1 = *(const h4*)(lds + tb1);

      h4 aA0 = __builtin_shufflevector(krA, krA, 0, 1, 2, 3);
      h4 aA1 = __builtin_shufflevector(krA, krA, 4, 5, 6, 7);
      h4 aB0 = __builtin_shufflevector(krB, krB, 0, 1, 2, 3);
      h4 aB1 = __builtin_shufflevector(krB, krB, 4, 5, 6, 7);

      // ---- scores, both streams: D row = k-offset 4g+reg, col = q ----
      f32x4 SA0 = mfma16(aA0, Bq0, Z);
      f32x4 SA1 = mfma16(aA1, Bq1, Z);
      f32x4 SB0 = mfma16(aB0, Bq0, Z);
      f32x4 SB1 = mfma16(aB1, Bq1, Z);

      // ---- exp (trans pipe) + pack: h4 IS the PV B-fragment ----
      h4 pA0, pA1, pB0, pB1;
      h2 u;
      u = cvt_pk_f16(__builtin_amdgcn_exp2f(SA0[0]),
                     __builtin_amdgcn_exp2f(SA0[1]));
      pA0[0] = u[0];
      pA0[1] = u[1];
      u = cvt_pk_f16(__builtin_amdgcn_exp2f(SA0[2]),
                     __builtin_amdgcn_exp2f(SA0[3]));
      pA0[2] = u[0];
      pA0[3] = u[1];
      u = cvt_pk_f16(__builtin_amdgcn_exp2f(SA1[0]),
                     __builtin_amdgcn_exp2f(SA1[1]));
      pA1[0] = u[0];
      pA1[1] = u[1];
      u = cvt_pk_f16(__builtin_amdgcn_exp2f(SA1[2]),
                     __builtin_amdgcn_exp2f(SA1[3]));
      pA1[2] = u[0];
      pA1[3] = u[1];
      u = cvt_pk_f16(__builtin_amdgcn_exp2f(SB0[0]),
                     __builtin_amdgcn_exp2f(SB0[1]));
      pB0[0] = u[0];
      pB0[1] = u[1];
      u = cvt_pk_f16(__builtin_amdgcn_exp2f(SB0[2]),
                     __builtin_amdgcn_exp2f(SB0[3]));
      pB0[2] = u[0];
      pB0[3] = u[1];
      u = cvt_pk_f16(__builtin_amdgcn_exp2f(SB1[0]),
                     __builtin_amdgcn_exp2f(SB1[1]));
      pB1[0] = u[0];
      pB1[1] = u[1];
      u = cvt_pk_f16(__builtin_amdgcn_exp2f(SB1[2]),
                     __builtin_amdgcn_exp2f(SB1[3]));
      pB1[2] = u[0];
      pB1[3] = u[1];

      // ---- PV (+denominator via ones-row), both streams ----
      C0a = mfma16(vA0, pA0, C0a);
      C1a = mfma16(vA1, pA1, C1a);
      C0b = mfma16(vB0, pB0, C0b);
      C1b = mfma16(vB1, pB1, C1b);

      sa += sadv;
      sb += sadv;
      ta0 += 16;
      ta1 += 16;
      tb0 += 16;
      tb1 += 16;
    }
  }

  // ---- merge the two streams in registers (free; no LDS, no barrier) ----
  f32x4 C0 = C0a + C0b;
  f32x4 C1 = C1a + C1b;

  // ---- per-wave epilogue: C cols = q (lane&15), rows = 4*(lane>>4)+reg ----
  const float den0 = __shfl(C0[0], 16 + n, 64);  // row 4 = ones-row sum
  const float den1 = __shfl(C1[0], 16 + n, 64);
  if (lane < 16) {  // group 0 holds rows 0-3 = numerator dims
    const float i0 = 1.0f / den0, i1 = 1.0f / den1;
    float m8[8] = {C0[0] * i0, C0[1] * i0, C0[2] * i0, C0[3] * i0,
                   C1[0] * i1, C1[1] * i1, C1[2] * i1, C1[3] * i1};
    float o[8];
#pragma unroll
    for (int e = 0; e < 8; ++e) {
      float s = 0.f;
#pragma unroll
      for (int f = 0; f < 8; ++f) s += m8[f] * Wout[e * 8 + f];
      o[e] = s;
    }
    const int q = blockIdx.x * 128 + w * 16 + n;
    float4* op = (float4*)(outp + ((size_t)b * NS + q) * 8);
    op[0] = make_float4(o[0], o[1], o[2], o[3]);
    op[1] = make_float4(o[4], o[5], o[6], o[7]);
  }
}

extern "C" void kernel_launch(void* const* d_in, const int* in_sizes, int n_in,
                              void* d_out, int out_size, void* d_ws,
                              size_t ws_size, hipStream_t stream) {
  const float* x = (const float*)d_in[0];      // [32, 2048, 8]
  const float* theta = (const float*)d_in[1];  // [8]
  const float* W = (const float*)d_in[2];      // [8, 8]
  float* out = (float*)d_out;                  // [32, 2048, 8]
  (void)d_ws;
  (void)ws_size;

  // 512 blocks (16 q-supertiles x 32 batches) of 8 waves; 37.4 KB LDS each
  // -> 2 blocks/CU, 16 waves/CU = 4 waves/SIMD (128-reg cap: no spills).
  attn_fused_kernel<<<dim3(NS / 128, NB), 512, 0, stream>>>(x, theta, W, out);
}